// Round 11
// baseline (379.861 us; speedup 1.0000x reference)
//
#include <hip/hip_runtime.h>
#include <hip/hip_bf16.h>

typedef __bf16 bf16;
typedef bf16 bf16x8 __attribute__((ext_vector_type(8)));
typedef float f32x4 __attribute__((ext_vector_type(4)));

static __device__ __forceinline__ f32x4 mfma16(bf16x8 a, bf16x8 b, f32x4 c) {
  return __builtin_amdgcn_mfma_f32_16x16x32_bf16(a, b, c, 0, 0, 0);
}

typedef __attribute__((address_space(3))) void lds_t;
typedef const __attribute__((address_space(1))) void gm_t;

#define N_SEG 18
#define TOTAL_CONV 2511616

struct ConvArgs { const void* src[N_SEG]; };

// canonicalize all 18 inputs -> bf16 arena + p passthrough; dtype flag computed
// per-block from x's exponent distribution (block 0 publishes for tail_k).
__global__ __launch_bounds__(256) void convall_k(ConvArgs a, bf16* __restrict__ dst,
                                                 void* __restrict__ outp,
                                                 int* __restrict__ flag) {
  const int ends[N_SEG] = {2097152, 2146304, 2162688, 2162816, 2228352, 2228864,
                           2294400, 2294912, 2360448, 2360960, 2362496, 2363008,
                           2428544, 2429056, 2494592, 2495104, 2511488, 2511616};
  // per-block probe: 512 shorts of x
  const unsigned short* xr = (const unsigned short*)a.src[0];
  int wild = 0;
#pragma unroll
  for (int j = 0; j < 2; j++) {
    unsigned short w = xr[threadIdx.x * 2 + j];
    int e = (w >> 7) & 0xFF;
    if (e < 110 || e > 134) wild++;
  }
#pragma unroll
  for (int off = 1; off < 64; off <<= 1) wild += __shfl_xor(wild, off);
  __shared__ int red[4];
  if ((threadIdx.x & 63) == 0) red[threadIdx.x >> 6] = wild;
  __syncthreads();
  const int isF32 = (red[0] + red[1] + red[2] + red[3]) > 64;
  if (blockIdx.x == 0 && threadIdx.x == 0) *flag = isF32;

  int i = blockIdx.x * 256 + threadIdx.x;
  if (i >= TOTAL_CONV) {
    int j = i - TOTAL_CONV;
    if (j < 49152) {
      if (isF32) ((float*)outp)[2097152 + j] = ((const float*)a.src[1])[j];
      else       ((bf16*)outp)[2097152 + j]  = ((const bf16*)a.src[1])[j];
    }
    return;
  }
  int s = 0;
  while (i >= ends[s]) s++;
  int j = i - (s ? ends[s - 1] : 0);
  if (isF32) dst[i] = (bf16)((const float*)a.src[s])[j];
  else       dst[i] = ((const bf16*)a.src[s])[j];
}

// fused pre-attention, 64-row tiles x head. q-epilogue folds scale*log2(e)
// so attn can use exp2 (v_exp_f32 is natively 2^x).
__global__ __launch_bounds__(256, 2) void pre_k(
    const bf16* __restrict__ x, const bf16* __restrict__ p,
    const bf16* __restrict__ f1w, const bf16* __restrict__ f1b,
    const bf16* __restrict__ pe1w, const bf16* __restrict__ pe1b,
    const bf16* __restrict__ pe2w, const bf16* __restrict__ pe2b,
    const bf16* __restrict__ Wq, const bf16* __restrict__ Bq,
    const bf16* __restrict__ Wk, const bf16* __restrict__ Bk,
    const bf16* __restrict__ Wv, const bf16* __restrict__ Bv,
    bf16* __restrict__ qo, bf16* __restrict__ ko, bf16* __restrict__ vo)
{
  const int lane = threadIdx.x & 63;
  const int wave = threadIdx.x >> 6;
  const int quad = lane >> 4;
  const int n15 = lane & 15;
  const int h = blockIdx.y;
  const int r0 = blockIdx.x * 64;
  const int wr = wave * 16;

  __shared__ bf16 tile[9216];   // phase A: [64 rows][136] ; phase B: [128 c][72]

  f32x4 acc[8];
  const f32x4 zz = {};

  // ---- pe1 = relu(p @ pe1w^T + pe1b), K=3 zero-padded MFMA ----
  {
    bf16x8 ap = {};
    if (quad == 0) {
      const bf16* pr = p + (long)(r0 + wr + n15) * 3;
      ap[0] = pr[0]; ap[1] = pr[1]; ap[2] = pr[2];
    }
#pragma unroll
    for (int ct = 0; ct < 8; ct++) {
      bf16x8 bw = {};
      if (quad == 0) {
        const bf16* wp = pe1w + ((long)h * 128 + ct * 16 + n15) * 3;
        bw[0] = wp[0]; bw[1] = wp[1]; bw[2] = wp[2];
      }
      acc[ct] = mfma16(ap, bw, zz);
    }
#pragma unroll
    for (int ct = 0; ct < 8; ct++) {
      const int col = ct * 16 + n15;
      const float bb = (float)pe1b[h * 128 + col];
#pragma unroll
      for (int r = 0; r < 4; r++)
        tile[(wr + quad * 4 + r) * 136 + col] = (bf16)fmaxf(acc[ct][r] + bb, 0.f);
    }
  }

  // ---- xh = pe @ pe2w^T + x @ f1w^T + (pe2b + f1b), single accumulator ----
#pragma unroll
  for (int ct = 0; ct < 8; ct++) acc[ct] = zz;
#pragma unroll
  for (int kk = 0; kk < 4; kk++) {
    const int ka = kk * 32 + quad * 8;
    bf16x8 a0 = *(const bf16x8*)&tile[(wr + n15) * 136 + ka];
#pragma unroll
    for (int ct = 0; ct < 8; ct++) {
      bf16x8 wf = *(const bf16x8*)(pe2w + (long)h * 16384 + (long)(ct * 16 + n15) * 128 + ka);
      acc[ct] = mfma16(a0, wf, acc[ct]);
    }
  }
#pragma unroll
  for (int kk = 0; kk < 4; kk++) {
    const int ka = kk * 32 + quad * 8;
    bf16x8 a0 = *(const bf16x8*)(x + (long)(r0 + wr + n15) * 128 + ka);
#pragma unroll
    for (int ct = 0; ct < 8; ct++) {
      bf16x8 wf = *(const bf16x8*)(f1w + (long)(ct * 16 + n15) * 128 + ka);
      acc[ct] = mfma16(a0, wf, acc[ct]);
    }
  }
#pragma unroll
  for (int ct = 0; ct < 8; ct++) {
    const int col = ct * 16 + n15;
    const float bv = (float)pe2b[h * 128 + col] + (float)f1b[col];
#pragma unroll
    for (int r = 0; r < 4; r++)
      tile[(wr + quad * 4 + r) * 136 + col] = (bf16)(acc[ct][r] + bv);
  }

  // ---- A-frags of xh (wave-local, DS pipe in-order per wave) ----
  bf16x8 af[4];
#pragma unroll
  for (int kk = 0; kk < 4; kk++)
    af[kk] = *(const bf16x8*)&tile[(wr + n15) * 136 + kk * 32 + quad * 8];

  // ---- q (scale*log2e folded) and k ----
#pragma unroll
  for (int m = 0; m < 2; m++) {
    f32x4 a2[8];
#pragma unroll
    for (int ct = 0; ct < 8; ct++) a2[ct] = zz;
    const bf16* Wm = (m == 0) ? Wq : Wk;
#pragma unroll
    for (int kk = 0; kk < 4; kk++) {
      const int ka = kk * 32 + quad * 8;
#pragma unroll
      for (int ct = 0; ct < 8; ct++) {
        bf16x8 wf = *(const bf16x8*)(Wm + (long)h * 16384 + (long)(ct * 16 + n15) * 128 + ka);
        a2[ct] = mfma16(af[kk], wf, a2[ct]);
      }
    }
    bf16* oz = ((m == 0) ? qo : ko) + (long)h * 2097152;
    const bf16* Bz = (m == 0) ? Bq : Bk;
    const float sc = (m == 0) ? 0.12751743f : 1.0f;  // (1/sqrt(128))*log2(e)
#pragma unroll
    for (int ct = 0; ct < 8; ct++) {
      const int col = ct * 16 + n15;
      const float bv = (float)Bz[h * 128 + col];
#pragma unroll
      for (int r = 0; r < 4; r++)
        oz[(long)(r0 + wr + quad * 4 + r) * 128 + col] = (bf16)((a2[ct][r] + bv) * sc);
    }
  }

  // ---- v, transposed store via LDS ----
  {
    f32x4 a2[8];
#pragma unroll
    for (int ct = 0; ct < 8; ct++) a2[ct] = zz;
#pragma unroll
    for (int kk = 0; kk < 4; kk++) {
      const int ka = kk * 32 + quad * 8;
#pragma unroll
      for (int ct = 0; ct < 8; ct++) {
        bf16x8 wf = *(const bf16x8*)(Wv + (long)h * 16384 + (long)(ct * 16 + n15) * 128 + ka);
        a2[ct] = mfma16(af[kk], wf, a2[ct]);
      }
    }
    __syncthreads();   // all waves done with xh tile
#pragma unroll
    for (int ct = 0; ct < 8; ct++) {
      const int col = ct * 16 + n15;
      const float bv = (float)Bv[h * 128 + col];
#pragma unroll
      for (int r = 0; r < 4; r++)
        tile[col * 72 + (wr + quad * 4 + r)] = (bf16)(a2[ct][r] + bv);
    }
    __syncthreads();
    bf16* vz = vo + (long)h * 2097152;
#pragma unroll
    for (int i = 0; i < 16; i++) {
      const int c = wave * 32 + i * 2 + (lane >> 5);
      const int m2 = (lane & 31) * 2;
      *(unsigned int*)&vz[(long)c * 16384 + r0 + m2] =
          *(const unsigned int*)&tile[c * 72 + m2];
    }
  }
}

// flash attention, SLIM-WAVE shape: 64 Q-rows/block, 4 waves x 16 rows,
// KV tile 64, single-buffered, no KV split (normalize + write cat in-kernel).
// Per-wave state: S[4]=16, qf[4]=16, Om[8]=32 AGPR -> unified ~125 regs ->
// 3-4 waves/SIMD; LDS 40KB -> up to 4 blocks/CU. Cross-block overlap covers
// the barrier drain. Staging via global_load_lds, swizzle on global side.
__global__ __launch_bounds__(256, 2) void attn_k(
    const bf16* __restrict__ Q, const bf16* __restrict__ Kg,
    const bf16* __restrict__ vT, bf16* __restrict__ cat)
{
  const int lane = threadIdx.x & 63;
  const int wave = threadIdx.x >> 6;
  const int quad = lane >> 4;
  const int n15 = lane & 15;
  const int b = blockIdx.y, h = blockIdx.z;
  const long qkBase = ((long)h * 4 + b) * 4096 * 128;
  const long vBase = (long)h * (128L * 16384) + (long)b * 4096;
  const int wrow = blockIdx.x * 64 + wave * 16;

  __shared__ bf16 Kt[64 * 128];    // addr(kv,c) = kv*128 + ((c>>3 ^ (kv&15))*8) + (c&7)
  __shared__ bf16 Vt[128 * 64];    // addr(c,kv) = c*64  + ((kv>>3 ^ (c&7))*8)  + (kv&7)
  __shared__ bf16 Pt[4][1024];     // addr(r,kv) = r*64  + ((kv>>3 ^ (r&7))*8)  + (kv&7)

  // Q fragments once (scale*log2e already folded by pre_k)
  bf16x8 qf[4];
#pragma unroll
  for (int kk = 0; kk < 4; kk++)
    qf[kk] = *(const bf16x8*)(Q + qkBase + (long)(wrow + n15) * 128 + kk * 32 + quad * 8);

  // async staging lane mapping (fixed per thread)
  const int krl  = lane >> 4;      // K: row within 4-row chunk
  const int kpch = lane & 15;      // K: physical 16B chunk
  const int vcl  = lane >> 3;      // V: c-row within 8-row chunk
  const int vpch = lane & 7;       // V: physical 16B chunk

  f32x4 Om[8] = {};
  float l_part[4] = {};

  for (int kv0 = 0; kv0 < 4096; kv0 += 64) {
    __syncthreads();
#pragma unroll
    for (int i = 0; i < 4; i++) {
      const int row = wave * 16 + i * 4 + krl;
      const int ch = kpch ^ (row & 15);
      __builtin_amdgcn_global_load_lds(
          (gm_t*)(Kg + qkBase + (long)(kv0 + row) * 128 + ch * 8),
          (lds_t*)&Kt[(wave * 16 + i * 4) * 128], 16, 0, 0);
    }
#pragma unroll
    for (int i = 0; i < 4; i++) {
      const int c = wave * 32 + i * 8 + vcl;
      const int vch = vpch ^ (c & 7);
      __builtin_amdgcn_global_load_lds(
          (gm_t*)(vT + vBase + (long)c * 16384 + kv0 + vch * 8),
          (lds_t*)&Vt[(wave * 32 + i * 8) * 64], 16, 0, 0);
    }
    __syncthreads();

    // S = Q @ K^T (16 q-rows x 64 kv)
    f32x4 S[4] = {};
#pragma unroll
    for (int kk = 0; kk < 4; kk++) {
#pragma unroll
      for (int ct = 0; ct < 4; ct++) {
        bf16x8 kf = *(const bf16x8*)&Kt[(ct * 16 + n15) * 128 + (((kk * 4 + quad) ^ n15) * 8)];
        S[ct] = mfma16(qf[kk], kf, S[ct]);
      }
    }

    // exp2 -> Pt (wave-local, in-order DS)
#pragma unroll
    for (int ct = 0; ct < 4; ct++)
#pragma unroll
      for (int r = 0; r < 4; r++) {
        float e = __builtin_amdgcn_exp2f(S[ct][r]);
        l_part[r] += e;
        const int row = quad * 4 + r;
        const int kv = ct * 16 + n15;
        Pt[wave][row * 64 + ((((kv >> 3) ^ (row & 7)) * 8)) + (kv & 7)] = (bf16)e;
      }

    // O += P @ V
#pragma unroll
    for (int kk = 0; kk < 2; kk++) {
      bf16x8 pf = *(const bf16x8*)&Pt[wave][n15 * 64 + (((kk * 4 + quad) ^ (n15 & 7)) * 8)];
#pragma unroll
      for (int ct = 0; ct < 8; ct++) {
        const int c = ct * 16 + n15;
        bf16x8 vf = *(const bf16x8*)&Vt[c * 64 + (((kk * 4 + quad) ^ (c & 7)) * 8)];
        Om[ct] = mfma16(pf, vf, Om[ct]);
      }
    }
  }

  // normalize + write concat layout
  float inv[4];
#pragma unroll
  for (int r = 0; r < 4; r++) {
    float s = l_part[r];
#pragma unroll
    for (int off = 1; off < 16; off <<= 1) s += __shfl_xor(s, off);
    inv[r] = 1.f / s;
  }
  const long ob = ((long)b * 4096 + wrow + quad * 4) * 512 + h * 128;
#pragma unroll
  for (int ct = 0; ct < 8; ct++)
#pragma unroll
    for (int r = 0; r < 4; r++)
      cat[ob + (long)r * 512 + ct * 16 + n15] = (bf16)(Om[ct][r] * inv[r]);
}

// fused tail: y1 = cat @ mh_w^T + mh_b ; y2 = y1 @ fcl2_w^T + fcl2_b ; LN ; + residual
__global__ __launch_bounds__(256) void tail_k(
    const bf16* __restrict__ cat,
    const bf16* __restrict__ mhw, const bf16* __restrict__ mhb,
    const bf16* __restrict__ f2w, const bf16* __restrict__ f2b,
    const void* __restrict__ xraw, void* __restrict__ outraw,
    const int* __restrict__ flag)
{
  const int lane = threadIdx.x & 63;
  const int wave = threadIdx.x >> 6;
  const int quad = lane >> 4;
  const int n15 = lane & 15;
  const int r0 = blockIdx.x * 64 + wave * 16;
  __shared__ bf16 y1t[64][136];

  f32x4 acc[8] = {};
  for (int k0 = 0; k0 < 512; k0 += 32) {
    const int ka = k0 + quad * 8;
    bf16x8 a0 = *(const bf16x8*)(cat + (long)(r0 + n15) * 512 + ka);
#pragma unroll
    for (int ct = 0; ct < 8; ct++) {
      bf16x8 wf = *(const bf16x8*)(mhw + (long)(ct * 16 + n15) * 512 + ka);
      acc[ct] = mfma16(a0, wf, acc[ct]);
    }
  }
#pragma unroll
  for (int ct = 0; ct < 8; ct++) {
    const float bv = (float)mhb[ct * 16 + n15];
#pragma unroll
    for (int r = 0; r < 4; r++)
      y1t[wave * 16 + quad * 4 + r][ct * 16 + n15] = (bf16)(acc[ct][r] + bv);
  }

  f32x4 acc2[8] = {};
  for (int k0 = 0; k0 < 128; k0 += 32) {
    const int ka = k0 + quad * 8;
    bf16x8 a0 = *(const bf16x8*)&y1t[wave * 16 + n15][ka];
#pragma unroll
    for (int ct = 0; ct < 8; ct++) {
      bf16x8 wf = *(const bf16x8*)(f2w + (long)(ct * 16 + n15) * 128 + ka);
      acc2[ct] = mfma16(a0, wf, acc2[ct]);
    }
  }

  float s1[4] = {}, s2[4] = {};
#pragma unroll
  for (int ct = 0; ct < 8; ct++) {
    const float bv = (float)f2b[ct * 16 + n15];
#pragma unroll
    for (int r = 0; r < 4; r++) {
      const float v = acc2[ct][r] + bv;
      acc2[ct][r] = v;
      s1[r] += v;
      s2[r] += v * v;
    }
  }
  float mu[4], inv[4];
#pragma unroll
  for (int r = 0; r < 4; r++) {
    float a = s1[r], b2 = s2[r];
#pragma unroll
    for (int off = 1; off < 16; off <<= 1) {
      a += __shfl_xor(a, off);
      b2 += __shfl_xor(b2, off);
    }
    mu[r] = a * (1.f / 128.f);
    const float var = fmaxf(b2 * (1.f / 128.f) - mu[r] * mu[r], 0.f);
    inv[r] = rsqrtf(var + 1e-5f);
  }

  const int isF32 = *flag;
#pragma unroll
  for (int ct = 0; ct < 8; ct++)
#pragma unroll
    for (int r = 0; r < 4; r++) {
      const long idx = (long)(r0 + quad * 4 + r) * 128 + ct * 16 + n15;
      const float resid = isF32 ? ((const float*)xraw)[idx]
                                : (float)((const bf16*)xraw)[idx];
      const float v = (acc2[ct][r] - mu[r]) * inv[r] + resid;
      if (isF32) ((float*)outraw)[idx] = v;
      else       ((bf16*)outraw)[idx] = (bf16)v;
    }
}

extern "C" void kernel_launch(void* const* d_in, const int* in_sizes, int n_in,
                              void* d_out, int out_size, void* d_ws, size_t ws_size,
                              hipStream_t stream)
{
  bf16* ws  = (bf16*)d_ws;
  bf16* q   = ws;                     // 8388608 elems [h][m][c]
  bf16* kb  = ws + 8388608;           // 8388608
  bf16* vt  = ws + 16777216;          // 8388608 (vT[h][c][m])
  bf16* cat = ws + 25165824;          // 8388608 (16384 x 512)
  const long AR = 33554432;           // bf16 canonical arena (2511616 elems)
  int* flag = (int*)(ws + 36066048);

  static const int counts[N_SEG] = {2097152, 49152, 16384, 128, 65536, 512, 65536, 512,
                                    65536, 512, 1536, 512, 65536, 512, 65536, 512, 16384, 128};
  long offs[N_SEG]; long o = AR;
  for (int i = 0; i < N_SEG; i++) { offs[i] = o; o += counts[i]; }
  bf16* xc    = ws + offs[0];
  bf16* pc    = ws + offs[1];
  bf16* f1w   = ws + offs[2];
  bf16* f1b   = ws + offs[3];
  bf16* hqw   = ws + offs[4];
  bf16* hqb   = ws + offs[5];
  bf16* hkw   = ws + offs[6];
  bf16* hkb   = ws + offs[7];
  bf16* hvw   = ws + offs[8];
  bf16* hvb   = ws + offs[9];
  bf16* pe1w  = ws + offs[10];
  bf16* pe1b  = ws + offs[11];
  bf16* pe2w  = ws + offs[12];
  bf16* pe2b  = ws + offs[13];
  bf16* mhw   = ws + offs[14];
  bf16* mhb   = ws + offs[15];
  bf16* f2w   = ws + offs[16];
  bf16* f2b   = ws + offs[17];

  ConvArgs ca;
  for (int i = 0; i < N_SEG; i++) ca.src[i] = d_in[i];
  convall_k<<<dim3((TOTAL_CONV + 49152 + 255) / 256), dim3(256), 0, stream>>>(ca, ws + AR, d_out, flag);

  dim3 blk(256);
  // q uses hk_w, k uses hq_w (reference name swap)
  pre_k<<<dim3(256, 4), blk, 0, stream>>>(xc, pc, f1w, f1b, pe1w, pe1b, pe2w, pe2b,
                                          hkw, hkb, hqw, hqb, hvw, hvb, q, kb, vt);
  attn_k<<<dim3(64, 4, 4), blk, 0, stream>>>(q, kb, vt, cat);
  tail_k<<<dim3(256), blk, 0, stream>>>(cat, mhw, mhb, f2w, f2b, d_in[0], d_out, flag);
}